// Round 6
// baseline (187.860 us; speedup 1.0000x reference)
//
#include <hip/hip_runtime.h>

#define NN 4096
#define IN_DIM 256
#define HID 64
#define HEADS 8

typedef __attribute__((ext_vector_type(4))) float f32x4;
typedef __attribute__((ext_vector_type(8))) short s16x8;
typedef unsigned short u16;
typedef unsigned long long u64;

__device__ inline u16 f2bf(float f) {
  union { float f; unsigned u; } v; v.f = f;
  unsigned r = (v.u + 0x7FFFu + ((v.u >> 16) & 1u)) >> 16;
  return (u16)r;
}
__device__ inline float bf2f(u16 b) {
  union { unsigned u; float f; } v; v.u = ((unsigned)b) << 16;
  return v.f;
}
__device__ __forceinline__ unsigned cvt_pk_bf16(float a, float b) {
  unsigned r;
  asm("v_cvt_pk_bf16_f32 %0, %1, %2" : "=v"(r) : "v"(a), "v"(b));
  return r;  // lo = bf16(a), hi = bf16(b)
}

// ---------------------------------------------------------------------------
// Kernel 0: detect adjacency element width (uint8 / int32 / int64).
// ---------------------------------------------------------------------------
__global__ void gat_detect(const void* __restrict__ adj, int* __restrict__ flag)
{
  const int lane = threadIdx.x;
  const unsigned char* a8 = (const unsigned char*)adj;
  const int* a32 = (const int*)adj;

  size_t i8 = (size_t)(4 * lane + 1) * 4097;      // diag byte if u8
  int p8 = a8[i8] != 0;

  size_t k = (size_t)(2 * lane + 1);              // odd
  int p32 = a32[k * 4097] != 0;                   // diag elem if i32
  int p64 = a32[2 * k * 4097] != 0;               // low word of diag if i64

  int ok8 = __all(p8), ok32 = __all(p32), ok64 = __all(p64);
  if (lane == 0) *flag = ok8 ? 0 : (ok32 ? 1 : (ok64 ? 2 : 1));
}

// ---------------------------------------------------------------------------
// Kernel 0b: pack adjacency into bitmask [4096 rows][64 u64 words].
// ---------------------------------------------------------------------------
__global__ __launch_bounds__(256) void gat_pack(
    const void* __restrict__ adj, const int* __restrict__ flag,
    u64* __restrict__ bits)
{
  const int mode = *flag;
  const int lane = threadIdx.x & 63;
  const int wave = (blockIdx.x * blockDim.x + threadIdx.x) >> 6;
  const int nwaves = (gridDim.x * blockDim.x) >> 6;
  const size_t nwords = (size_t)NN * NN / 64;

  for (size_t w = wave; w < nwords; w += nwaves) {
    size_t e = w * 64 + lane;
    int on;
    if (mode == 1)      on = ((const int*)adj)[e] != 0;
    else if (mode == 0) on = ((const unsigned char*)adj)[e] != 0;
    else                on = ((const long long*)adj)[e] != 0;
    u64 b = __ballot(on);
    if (lane == 0) bits[w] = b;
  }
}

// ---------------------------------------------------------------------------
// Kernel 1: H = x @ W^T  (4096 x 512), f32 out + transposed bf16 copy.
// 3-term bf16 split (hi*hi + hi*lo + lo*hi) for ~f32 accuracy via MFMA.
// ---------------------------------------------------------------------------
__global__ __launch_bounds__(256) void gat_gemm1(
    const float* __restrict__ x, const float* __restrict__ W,
    float* __restrict__ Hf, u16* __restrict__ Hbt)
{
  __shared__ u16 xhi[64 * 72], xlo[64 * 72], whi[64 * 72], wlo[64 * 72];
  const int nb = blockIdx.x;   // node block (rows)
  const int ob = blockIdx.y;   // out block  (cols) == head
  const int t = threadIdx.x;
  const int lane = t & 63, wid = t >> 6;
  const int wr = wid >> 1, wc = wid & 1;
  const int g = lane >> 4;

  f32x4 acc[2][2] = {};

  const int sn = t >> 2;          // staging row 0..63
  const int skc = (t & 3) * 16;   // staging k offset within 64-chunk

  for (int kb = 0; kb < 4; ++kb) {
    const float* xr = x + (size_t)(nb * 64 + sn) * IN_DIM + kb * 64 + skc;
    const float* wr_p = W + (size_t)(ob * 64 + sn) * IN_DIM + kb * 64 + skc;
#pragma unroll
    for (int c = 0; c < 4; ++c) {
      float4 xv = ((const float4*)xr)[c];
      float4 wv = ((const float4*)wr_p)[c];
      float xf[4] = {xv.x, xv.y, xv.z, xv.w};
      float wf[4] = {wv.x, wv.y, wv.z, wv.w};
      u16 xh[4], xl[4], wh[4], wl[4];
#pragma unroll
      for (int e = 0; e < 4; ++e) {
        xh[e] = f2bf(xf[e]); xl[e] = f2bf(xf[e] - bf2f(xh[e]));
        wh[e] = f2bf(wf[e]); wl[e] = f2bf(wf[e] - bf2f(wh[e]));
      }
      int base = sn * 72 + skc + c * 4;
      *(ushort4*)(xhi + base) = make_ushort4(xh[0], xh[1], xh[2], xh[3]);
      *(ushort4*)(xlo + base) = make_ushort4(xl[0], xl[1], xl[2], xl[3]);
      *(ushort4*)(whi + base) = make_ushort4(wh[0], wh[1], wh[2], wh[3]);
      *(ushort4*)(wlo + base) = make_ushort4(wl[0], wl[1], wl[2], wl[3]);
    }
    __syncthreads();
#pragma unroll
    for (int ks = 0; ks < 2; ++ks) {
      const int k0 = ks * 32 + g * 8;
      s16x8 ah[2], al[2], bh[2], bl[2];
#pragma unroll
      for (int nf = 0; nf < 2; ++nf) {
        int row = wr * 32 + nf * 16 + (lane & 15);
        ah[nf] = *(const s16x8*)(xhi + row * 72 + k0);
        al[nf] = *(const s16x8*)(xlo + row * 72 + k0);
      }
#pragma unroll
      for (int of = 0; of < 2; ++of) {
        int row = wc * 32 + of * 16 + (lane & 15);
        bh[of] = *(const s16x8*)(whi + row * 72 + k0);
        bl[of] = *(const s16x8*)(wlo + row * 72 + k0);
      }
#pragma unroll
      for (int nf = 0; nf < 2; ++nf)
#pragma unroll
        for (int of = 0; of < 2; ++of) {
          acc[nf][of] = __builtin_amdgcn_mfma_f32_16x16x32_bf16(ah[nf], bh[of], acc[nf][of], 0, 0, 0);
          acc[nf][of] = __builtin_amdgcn_mfma_f32_16x16x32_bf16(ah[nf], bl[of], acc[nf][of], 0, 0, 0);
          acc[nf][of] = __builtin_amdgcn_mfma_f32_16x16x32_bf16(al[nf], bh[of], acc[nf][of], 0, 0, 0);
        }
    }
    __syncthreads();
  }

  // epilogue: f32 H + transposed bf16 copy (via LDS, reuse xhi)
#pragma unroll
  for (int nf = 0; nf < 2; ++nf)
#pragma unroll
    for (int of = 0; of < 2; ++of)
#pragma unroll
      for (int r = 0; r < 4; ++r) {
        int nloc = wr * 32 + nf * 16 + g * 4 + r;
        int oloc = wc * 32 + of * 16 + (lane & 15);
        Hf[(size_t)(nb * 64 + nloc) * 512 + ob * 64 + oloc] = acc[nf][of][r];
      }
  u16* Ct = xhi;  // [64 o][72 n]
#pragma unroll
  for (int nf = 0; nf < 2; ++nf)
#pragma unroll
    for (int of = 0; of < 2; ++of)
#pragma unroll
      for (int r = 0; r < 4; ++r) {
        int nloc = wr * 32 + nf * 16 + g * 4 + r;
        int oloc = wc * 32 + of * 16 + (lane & 15);
        Ct[oloc * 72 + nloc] = f2bf(acc[nf][of][r]);
      }
  __syncthreads();
  {
    int o = t >> 2, nc = (t & 3) * 16;
#pragma unroll
    for (int c = 0; c < 2; ++c) {
      s16x8 v = *(const s16x8*)(Ct + o * 72 + nc + c * 8);
      *(s16x8*)(Hbt + (size_t)(ob * 64 + o) * NN + nb * 64 + nc + c * 8) = v;
    }
  }
}

// ---------------------------------------------------------------------------
// Kernel 2: src/dst attention scores -> transposed layout [h][node].
// ---------------------------------------------------------------------------
__global__ __launch_bounds__(256) void gat_scores(
    const float* __restrict__ Hf, const float* __restrict__ a_src,
    const float* __restrict__ a_dst, float* __restrict__ s_srcT,
    float* __restrict__ s_dstT)
{
  int node = blockIdx.x * 4 + (threadIdx.x >> 6);
  int lane = threadIdx.x & 63;
  int h = lane >> 3, c = lane & 7;
  const float* hrow = Hf + (size_t)node * 512 + h * 64 + c * 8;
  const float* as = a_src + h * 64 + c * 8;
  const float* ad = a_dst + h * 64 + c * 8;
  float vs = 0.f, vd = 0.f;
#pragma unroll
  for (int e = 0; e < 8; ++e) { float hv = hrow[e]; vs += hv * as[e]; vd += hv * ad[e]; }
#pragma unroll
  for (int m = 1; m < 8; m <<= 1) { vs += __shfl_xor(vs, m); vd += __shfl_xor(vd, m); }
  if (c == 0) { s_srcT[h * NN + node] = vs; s_dstT[h * NN + node] = vd; }
}

// ---------------------------------------------------------------------------
// Kernel 2b: per-head global max of dst scores (upper bound for fixed-m).
// ---------------------------------------------------------------------------
__global__ __launch_bounds__(512) void gat_dmax(
    const float* __restrict__ s_dstT, float* __restrict__ Mh)
{
  const int w = threadIdx.x >> 6, lane = threadIdx.x & 63;
  const float* p = s_dstT + (size_t)w * NN;
  float m = -INFINITY;
#pragma unroll
  for (int it = 0; it < 16; ++it) {
    f32x4 v = *(const f32x4*)(p + (it * 64 + lane) * 4);
    m = fmaxf(fmaxf(fmaxf(m, v[0]), v[1]), fmaxf(v[2], v[3]));
  }
#pragma unroll
  for (int s = 1; s < 64; s <<= 1) m = fmaxf(m, __shfl_xor(m, s));
  if (lane == 0) Mh[w] = m;
}

// ---------------------------------------------------------------------------
// Kernel 3: flash-GAT, fixed-m softmax, A-fragment DOUBLE-BUFFERED (unroll-2):
// loads for tile j+1 issue before tile j's softmax+MFMA -> load-use distance
// = one full tile body. P-pack via v_cvt_pk_bf16_f32 (1 instr / 2 elems).
// Mask applied after exp (safe: z <= m_i even for masked entries).
// 1024 threads = 16 waves = 8 heads x 2 j-halves; block = 16 i-rows.
// ---------------------------------------------------------------------------
__global__ __launch_bounds__(1024) void gat_flash(
    const u64* __restrict__ bits, const u16* __restrict__ Hbt,
    const float* __restrict__ s_srcT, const float* __restrict__ s_dstT,
    const float* __restrict__ Mh, float* __restrict__ out)
{
  __shared__ float Abuf[8][16][66];   // padded: conflict-free
  __shared__ float Lbuf[8][16];

  const int t = threadIdx.x, lane = t & 63, w = t >> 6;
  const int h = w & 7, jsw = w >> 3;
  const int blk = blockIdx.x;
  const int i_loc = lane & 15, g = lane >> 4, j0 = g * 8;

  const float s_i = s_srcT[(size_t)h * NN + blk * 16 + i_loc];
  float m_i = s_i + Mh[h];
  m_i = fmaxf(m_i, 0.2f * m_i);                 // lrelu(s_i + M_h) >= all z
  const float L2E = 1.44269504f;
  const float mL = m_i * L2E;

  const u16* hb = Hbt + (size_t)(h * 64 + i_loc) * NN;
  const float* dT = s_dstT + (size_t)h * NN;
  const u64* brow = bits + (size_t)(blk * 16 + i_loc) * 64;

  f32x4 acc[4] = {};
  f32x4 lacc = {0.f, 0.f, 0.f, 0.f};

  const int jt0 = jsw * 32, jt1 = jt0 + 32;

#define LOADA(BUF, JT) do {                                           \
    const u16* p_ = hb + (JT) * 64 + j0;                              \
    _Pragma("unroll")                                                 \
    for (int fb = 0; fb < 4; ++fb) {                                  \
      BUF[fb][0] = *(const s16x8*)(p_ + (size_t)fb * 16 * NN);        \
      BUF[fb][1] = *(const s16x8*)(p_ + (size_t)fb * 16 * NN + 32);   \
    }                                                                 \
  } while (0)

#define QUAD(DV, MBITS, SH, PW0, PW1, LI) do {                        \
    float z0 = s_i + DV[0], z1 = s_i + DV[1];                         \
    float z2 = s_i + DV[2], z3 = s_i + DV[3];                         \
    z0 = fmaxf(z0, 0.2f * z0); z1 = fmaxf(z1, 0.2f * z1);             \
    z2 = fmaxf(z2, 0.2f * z2); z3 = fmaxf(z3, 0.2f * z3);             \
    float e0 = __builtin_amdgcn_exp2f(__builtin_fmaf(z0, L2E, -mL));  \
    float e1 = __builtin_amdgcn_exp2f(__builtin_fmaf(z1, L2E, -mL));  \
    float e2 = __builtin_amdgcn_exp2f(__builtin_fmaf(z2, L2E, -mL));  \
    float e3 = __builtin_amdgcn_exp2f(__builtin_fmaf(z3, L2E, -mL));  \
    e0 = ((MBITS >> (SH + 0)) & 1u) ? e0 : 0.f;                       \
    e1 = ((MBITS >> (SH + 1)) & 1u) ? e1 : 0.f;                       \
    e2 = ((MBITS >> (SH + 2)) & 1u) ? e2 : 0.f;                       \
    e3 = ((MBITS >> (SH + 3)) & 1u) ? e3 : 0.f;                       \
    lacc[LI] += (e0 + e1) + (e2 + e3);                                \
    PW0 = cvt_pk_bf16(e0, e1); PW1 = cvt_pk_bf16(e2, e3);             \
  } while (0)

  // TILE: consume prefetched am_n/d_n for current tile, prefetch JNEXT's,
  // softmax+pack, MFMA with BUF.
#define TILE(BUF, JNEXT) do {                                         \
    const u64 am_ = am_n;                                             \
    f32x4 d0_ = d_n[0], d1_ = d_n[1], d2_ = d_n[2], d3_ = d_n[3];     \
    am_n = brow[JNEXT];                                               \
    d_n[0] = *(const f32x4*)(dT + (JNEXT) * 64 + j0);                 \
    d_n[1] = *(const f32x4*)(dT + (JNEXT) * 64 + j0 + 4);             \
    d_n[2] = *(const f32x4*)(dT + (JNEXT) * 64 + 32 + j0);            \
    d_n[3] = *(const f32x4*)(dT + (JNEXT) * 64 + 32 + j0 + 4);        \
    const unsigned amlo_ = (unsigned)(am_ >> j0);                     \
    const unsigned amhi_ = (unsigned)(am_ >> (32 + j0));              \
    union { unsigned w_[4]; s16x8 v_; } P0, P1;                       \
    QUAD(d0_, amlo_, 0, P0.w_[0], P0.w_[1], 0);                       \
    QUAD(d1_, amlo_, 4, P0.w_[2], P0.w_[3], 1);                       \
    QUAD(d2_, amhi_, 0, P1.w_[0], P1.w_[1], 2);                       \
    QUAD(d3_, amhi_, 4, P1.w_[2], P1.w_[3], 3);                       \
    _Pragma("unroll")                                                 \
    for (int fb = 0; fb < 4; ++fb) {                                  \
      acc[fb] = __builtin_amdgcn_mfma_f32_16x16x32_bf16(BUF[fb][0], P0.v_, acc[fb], 0, 0, 0); \
      acc[fb] = __builtin_amdgcn_mfma_f32_16x16x32_bf16(BUF[fb][1], P1.v_, acc[fb], 0, 0, 0); \
    }                                                                 \
  } while (0)

  s16x8 bufA[4][2], bufB[4][2];
  LOADA(bufA, jt0);
  u64 am_n = brow[jt0];
  f32x4 d_n[4];
  d_n[0] = *(const f32x4*)(dT + jt0 * 64 + j0);
  d_n[1] = *(const f32x4*)(dT + jt0 * 64 + j0 + 4);
  d_n[2] = *(const f32x4*)(dT + jt0 * 64 + 32 + j0);
  d_n[3] = *(const f32x4*)(dT + jt0 * 64 + 32 + j0 + 4);

  for (int it = 0; it < 16; ++it) {
    const int jA = jt0 + 2 * it;
    const int jB = jA + 1;
    const int jC = (it < 15) ? jB + 1 : jB;   // clamped at the end
    // half A: issue jB's A-loads, process jA from bufA
    LOADA(bufB, jB);
    TILE(bufA, jB);
    // half B: issue jC's A-loads, process jB from bufB
    LOADA(bufA, jC);
    TILE(bufB, jC);
  }
#undef LOADA
#undef QUAD
#undef TILE

  // l for this wave's j-half: sum 4 partials, then over the 4 g-groups
  float l_run = (lacc[0] + lacc[1]) + (lacc[2] + lacc[3]);
  l_run += __shfl_xor(l_run, 16);
  l_run += __shfl_xor(l_run, 32);

  // epilogue: plain-add merge of the two j-halves (same m!), then head-mean
  if (jsw == 1) {
#pragma unroll
    for (int fb = 0; fb < 4; ++fb)
#pragma unroll
      for (int r = 0; r < 4; ++r)
        Abuf[h][i_loc][fb * 16 + g * 4 + r] = acc[fb][r];
    if (lane < 16) Lbuf[h][i_loc] = l_run;
  }
  __syncthreads();
  if (jsw == 0) {
    float invL = 1.f / (l_run + Lbuf[h][i_loc]);
#pragma unroll
    for (int fb = 0; fb < 4; ++fb)
#pragma unroll
      for (int r = 0; r < 4; ++r) {
        int f = fb * 16 + g * 4 + r;
        Abuf[h][i_loc][f] = (acc[fb][r] + Abuf[h][i_loc][f]) * invL;
      }
  }
  __syncthreads();
  {
    int i = t >> 6, f = t & 63;
    float s = 0.f;
#pragma unroll
    for (int hh = 0; hh < 8; ++hh) s += Abuf[hh][i][f];
    out[(size_t)(blk * 16 + i) * 64 + f] = s * 0.125f;
  }
}

extern "C" void kernel_launch(void* const* d_in, const int* in_sizes, int n_in,
                              void* d_out, int out_size, void* d_ws, size_t ws_size,
                              hipStream_t stream)
{
  const float* x = (const float*)d_in[0];
  const void* adj = d_in[1];
  const float* W = (const float*)d_in[2];
  const float* a_src = (const float*)d_in[3];
  const float* a_dst = (const float*)d_in[4];
  float* out = (float*)d_out;

  char* ws = (char*)d_ws;
  float* Hf = (float*)ws;                                   // 8 MB
  u16* Hbt = (u16*)(ws + 8 * 1024 * 1024);                  // 4 MB  [8][64][4096] bf16
  float* s_srcT = (float*)(ws + 12 * 1024 * 1024);          // 128 KB [8][4096]
  float* s_dstT = (float*)(ws + 12 * 1024 * 1024 + 128 * 1024);
  int* flag = (int*)(ws + 12 * 1024 * 1024 + 256 * 1024);
  float* Mh = (float*)(ws + 12 * 1024 * 1024 + 384 * 1024); // 32 B
  u64* bits = (u64*)(ws + 12 * 1024 * 1024 + 512 * 1024);   // 2 MB

  gat_detect<<<1, 64, 0, stream>>>(adj, flag);
  gat_pack<<<2048, 256, 0, stream>>>(adj, flag, bits);
  gat_gemm1<<<dim3(64, 8), 256, 0, stream>>>(x, W, Hf, Hbt);
  gat_scores<<<1024, 256, 0, stream>>>(Hf, a_src, a_dst, s_srcT, s_dstT);
  gat_dmax<<<1, 512, 0, stream>>>(s_dstT, Mh);
  gat_flash<<<256, 1024, 0, stream>>>(bits, Hbt, s_srcT, s_dstT, Mh, out);
}

// Round 7
// 181.703 us; speedup vs baseline: 1.0339x; 1.0339x over previous
//
#include <hip/hip_runtime.h>

#define NN 4096
#define IN_DIM 256
#define HID 64
#define HEADS 8

typedef __attribute__((ext_vector_type(4))) float f32x4;
typedef __attribute__((ext_vector_type(8))) short s16x8;
typedef unsigned short u16;
typedef unsigned long long u64;

__device__ inline u16 f2bf(float f) {
  union { float f; unsigned u; } v; v.f = f;
  unsigned r = (v.u + 0x7FFFu + ((v.u >> 16) & 1u)) >> 16;
  return (u16)r;
}
__device__ inline float bf2f(u16 b) {
  union { unsigned u; float f; } v; v.u = ((unsigned)b) << 16;
  return v.f;
}
__device__ __forceinline__ unsigned cvt_pk_bf16(float a, float b) {
  unsigned r;
  asm("v_cvt_pk_bf16_f32 %0, %1, %2" : "=v"(r) : "v"(a), "v"(b));
  return r;  // lo = bf16(a), hi = bf16(b)
}

// ---------------------------------------------------------------------------
// Kernel 0: detect adjacency element width (uint8 / int32 / int64).
// ---------------------------------------------------------------------------
__global__ void gat_detect(const void* __restrict__ adj, int* __restrict__ flag)
{
  const int lane = threadIdx.x;
  const unsigned char* a8 = (const unsigned char*)adj;
  const int* a32 = (const int*)adj;

  size_t i8 = (size_t)(4 * lane + 1) * 4097;      // diag byte if u8
  int p8 = a8[i8] != 0;

  size_t k = (size_t)(2 * lane + 1);              // odd
  int p32 = a32[k * 4097] != 0;                   // diag elem if i32
  int p64 = a32[2 * k * 4097] != 0;               // low word of diag if i64

  int ok8 = __all(p8), ok32 = __all(p32), ok64 = __all(p64);
  if (lane == 0) *flag = ok8 ? 0 : (ok32 ? 1 : (ok64 ? 2 : 1));
}

// ---------------------------------------------------------------------------
// Kernel 0b: pack adjacency into bitmask [4096 rows][64 u64 words].
// ---------------------------------------------------------------------------
__global__ __launch_bounds__(256) void gat_pack(
    const void* __restrict__ adj, const int* __restrict__ flag,
    u64* __restrict__ bits)
{
  const int mode = *flag;
  const int lane = threadIdx.x & 63;
  const int wave = (blockIdx.x * blockDim.x + threadIdx.x) >> 6;
  const int nwaves = (gridDim.x * blockDim.x) >> 6;
  const size_t nwords = (size_t)NN * NN / 64;

  for (size_t w = wave; w < nwords; w += nwaves) {
    size_t e = w * 64 + lane;
    int on;
    if (mode == 1)      on = ((const int*)adj)[e] != 0;
    else if (mode == 0) on = ((const unsigned char*)adj)[e] != 0;
    else                on = ((const long long*)adj)[e] != 0;
    u64 b = __ballot(on);
    if (lane == 0) bits[w] = b;
  }
}

// ---------------------------------------------------------------------------
// Kernel 1: H = x @ W^T  (4096 x 512), f32 out + TILED bf16 copy:
// Hbt2[h][jt][f][j_in] -- one contiguous 8KB block per (head, 64-col j-tile),
// so flash's A-loads are a contiguous stream (no 8KB power-of-2 lane stride
// -> no L2 channel serialization).
// ---------------------------------------------------------------------------
__global__ __launch_bounds__(256) void gat_gemm1(
    const float* __restrict__ x, const float* __restrict__ W,
    float* __restrict__ Hf, u16* __restrict__ Hbt)
{
  __shared__ u16 xhi[64 * 72], xlo[64 * 72], whi[64 * 72], wlo[64 * 72];
  const int nb = blockIdx.x;   // node block (rows) == j-tile index
  const int ob = blockIdx.y;   // out block  (cols) == head
  const int t = threadIdx.x;
  const int lane = t & 63, wid = t >> 6;
  const int wr = wid >> 1, wc = wid & 1;
  const int g = lane >> 4;

  f32x4 acc[2][2] = {};

  const int sn = t >> 2;          // staging row 0..63
  const int skc = (t & 3) * 16;   // staging k offset within 64-chunk

  for (int kb = 0; kb < 4; ++kb) {
    const float* xr = x + (size_t)(nb * 64 + sn) * IN_DIM + kb * 64 + skc;
    const float* wr_p = W + (size_t)(ob * 64 + sn) * IN_DIM + kb * 64 + skc;
#pragma unroll
    for (int c = 0; c < 4; ++c) {
      float4 xv = ((const float4*)xr)[c];
      float4 wv = ((const float4*)wr_p)[c];
      float xf[4] = {xv.x, xv.y, xv.z, xv.w};
      float wf[4] = {wv.x, wv.y, wv.z, wv.w};
      u16 xh[4], xl[4], wh[4], wl[4];
#pragma unroll
      for (int e = 0; e < 4; ++e) {
        xh[e] = f2bf(xf[e]); xl[e] = f2bf(xf[e] - bf2f(xh[e]));
        wh[e] = f2bf(wf[e]); wl[e] = f2bf(wf[e] - bf2f(wh[e]));
      }
      int base = sn * 72 + skc + c * 4;
      *(ushort4*)(xhi + base) = make_ushort4(xh[0], xh[1], xh[2], xh[3]);
      *(ushort4*)(xlo + base) = make_ushort4(xl[0], xl[1], xl[2], xl[3]);
      *(ushort4*)(whi + base) = make_ushort4(wh[0], wh[1], wh[2], wh[3]);
      *(ushort4*)(wlo + base) = make_ushort4(wl[0], wl[1], wl[2], wl[3]);
    }
    __syncthreads();
#pragma unroll
    for (int ks = 0; ks < 2; ++ks) {
      const int k0 = ks * 32 + g * 8;
      s16x8 ah[2], al[2], bh[2], bl[2];
#pragma unroll
      for (int nf = 0; nf < 2; ++nf) {
        int row = wr * 32 + nf * 16 + (lane & 15);
        ah[nf] = *(const s16x8*)(xhi + row * 72 + k0);
        al[nf] = *(const s16x8*)(xlo + row * 72 + k0);
      }
#pragma unroll
      for (int of = 0; of < 2; ++of) {
        int row = wc * 32 + of * 16 + (lane & 15);
        bh[of] = *(const s16x8*)(whi + row * 72 + k0);
        bl[of] = *(const s16x8*)(wlo + row * 72 + k0);
      }
#pragma unroll
      for (int nf = 0; nf < 2; ++nf)
#pragma unroll
        for (int of = 0; of < 2; ++of) {
          acc[nf][of] = __builtin_amdgcn_mfma_f32_16x16x32_bf16(ah[nf], bh[of], acc[nf][of], 0, 0, 0);
          acc[nf][of] = __builtin_amdgcn_mfma_f32_16x16x32_bf16(ah[nf], bl[of], acc[nf][of], 0, 0, 0);
          acc[nf][of] = __builtin_amdgcn_mfma_f32_16x16x32_bf16(al[nf], bh[of], acc[nf][of], 0, 0, 0);
        }
    }
    __syncthreads();
  }

  // epilogue: f32 H + tiled bf16 copy (via LDS, reuse xhi)
#pragma unroll
  for (int nf = 0; nf < 2; ++nf)
#pragma unroll
    for (int of = 0; of < 2; ++of)
#pragma unroll
      for (int r = 0; r < 4; ++r) {
        int nloc = wr * 32 + nf * 16 + g * 4 + r;
        int oloc = wc * 32 + of * 16 + (lane & 15);
        Hf[(size_t)(nb * 64 + nloc) * 512 + ob * 64 + oloc] = acc[nf][of][r];
      }
  u16* Ct = xhi;  // [64 o][72 n]
#pragma unroll
  for (int nf = 0; nf < 2; ++nf)
#pragma unroll
    for (int of = 0; of < 2; ++of)
#pragma unroll
      for (int r = 0; r < 4; ++r) {
        int nloc = wr * 32 + nf * 16 + g * 4 + r;
        int oloc = wc * 32 + of * 16 + (lane & 15);
        Ct[oloc * 72 + nloc] = f2bf(acc[nf][of][r]);
      }
  __syncthreads();
  {
    int o = t >> 2, nc = (t & 3) * 16;
    // Hbt2[(head ob, jt nb)] tile base + f(o)*64 + j_in
    u16* dst = Hbt + ((size_t)(ob * 64 + nb) * 64 + o) * 64 + nc;
#pragma unroll
    for (int c = 0; c < 2; ++c) {
      s16x8 v = *(const s16x8*)(Ct + o * 72 + nc + c * 8);
      *(s16x8*)(dst + c * 8) = v;
    }
  }
}

// ---------------------------------------------------------------------------
// Kernel 2: src/dst attention scores -> transposed layout [h][node].
// ---------------------------------------------------------------------------
__global__ __launch_bounds__(256) void gat_scores(
    const float* __restrict__ Hf, const float* __restrict__ a_src,
    const float* __restrict__ a_dst, float* __restrict__ s_srcT,
    float* __restrict__ s_dstT)
{
  int node = blockIdx.x * 4 + (threadIdx.x >> 6);
  int lane = threadIdx.x & 63;
  int h = lane >> 3, c = lane & 7;
  const float* hrow = Hf + (size_t)node * 512 + h * 64 + c * 8;
  const float* as = a_src + h * 64 + c * 8;
  const float* ad = a_dst + h * 64 + c * 8;
  float vs = 0.f, vd = 0.f;
#pragma unroll
  for (int e = 0; e < 8; ++e) { float hv = hrow[e]; vs += hv * as[e]; vd += hv * ad[e]; }
#pragma unroll
  for (int m = 1; m < 8; m <<= 1) { vs += __shfl_xor(vs, m); vd += __shfl_xor(vd, m); }
  if (c == 0) { s_srcT[h * NN + node] = vs; s_dstT[h * NN + node] = vd; }
}

// ---------------------------------------------------------------------------
// Kernel 2b: per-head global max of dst scores (upper bound for fixed-m).
// ---------------------------------------------------------------------------
__global__ __launch_bounds__(512) void gat_dmax(
    const float* __restrict__ s_dstT, float* __restrict__ Mh)
{
  const int w = threadIdx.x >> 6, lane = threadIdx.x & 63;
  const float* p = s_dstT + (size_t)w * NN;
  float m = -INFINITY;
#pragma unroll
  for (int it = 0; it < 16; ++it) {
    f32x4 v = *(const f32x4*)(p + (it * 64 + lane) * 4);
    m = fmaxf(fmaxf(fmaxf(m, v[0]), v[1]), fmaxf(v[2], v[3]));
  }
#pragma unroll
  for (int s = 1; s < 64; s <<= 1) m = fmaxf(m, __shfl_xor(m, s));
  if (lane == 0) Mh[w] = m;
}

// ---------------------------------------------------------------------------
// Kernel 3: flash-GAT, fixed-m softmax, tiled A layout (contiguous 8KB per
// (h,jt) tile), A double-buffered in registers (launch_bounds (1024,4) ->
// VGPR cap 128, no spill). 1024 threads = 16 waves = 8 heads x 2 j-halves.
// ---------------------------------------------------------------------------
__global__ __launch_bounds__(1024, 4) void gat_flash(
    const u64* __restrict__ bits, const u16* __restrict__ Hbt,
    const float* __restrict__ s_srcT, const float* __restrict__ s_dstT,
    const float* __restrict__ Mh, float* __restrict__ out)
{
  __shared__ float Abuf[8][16][66];   // padded: conflict-free
  __shared__ float Lbuf[8][16];

  const int t = threadIdx.x, lane = t & 63, w = t >> 6;
  const int h = w & 7, jsw = w >> 3;
  const int blk = blockIdx.x;
  const int i_loc = lane & 15, g = lane >> 4, j0 = g * 8;

  const float s_i = s_srcT[(size_t)h * NN + blk * 16 + i_loc];
  float m_i = s_i + Mh[h];
  m_i = fmaxf(m_i, 0.2f * m_i);                 // lrelu(s_i + M_h) >= all z
  const float L2E = 1.44269504f;
  const float mL = m_i * L2E;

  // tiled A: lane base within a (h,jt) 4096-elem tile
  const u16* hb0 = Hbt + (size_t)h * 64 * 4096 + i_loc * 64 + j0;
  const float* dT = s_dstT + (size_t)h * NN;
  const u64* brow = bits + (size_t)(blk * 16 + i_loc) * 64;

  f32x4 acc[4] = {};
  f32x4 lacc = {0.f, 0.f, 0.f, 0.f};

  const int jt0 = jsw * 32, jt1 = jt0 + 32;

#define LOADA(BUF, JT) do {                                           \
    const u16* p_ = hb0 + (size_t)(JT) * 4096;                        \
    _Pragma("unroll")                                                 \
    for (int fb = 0; fb < 4; ++fb) {                                  \
      BUF[fb][0] = *(const s16x8*)(p_ + fb * 1024);                   \
      BUF[fb][1] = *(const s16x8*)(p_ + fb * 1024 + 32);              \
    }                                                                 \
  } while (0)

#define QUAD(DP, MBITS, SH, PW0, PW1, LI) do {                        \
    f32x4 dv_ = *(const f32x4*)(DP);                                  \
    float z0 = s_i + dv_[0], z1 = s_i + dv_[1];                       \
    float z2 = s_i + dv_[2], z3 = s_i + dv_[3];                       \
    z0 = fmaxf(z0, 0.2f * z0); z1 = fmaxf(z1, 0.2f * z1);             \
    z2 = fmaxf(z2, 0.2f * z2); z3 = fmaxf(z3, 0.2f * z3);             \
    float e0 = __builtin_amdgcn_exp2f(__builtin_fmaf(z0, L2E, -mL));  \
    float e1 = __builtin_amdgcn_exp2f(__builtin_fmaf(z1, L2E, -mL));  \
    float e2 = __builtin_amdgcn_exp2f(__builtin_fmaf(z2, L2E, -mL));  \
    float e3 = __builtin_amdgcn_exp2f(__builtin_fmaf(z3, L2E, -mL));  \
    e0 = ((MBITS >> (SH + 0)) & 1u) ? e0 : 0.f;                       \
    e1 = ((MBITS >> (SH + 1)) & 1u) ? e1 : 0.f;                       \
    e2 = ((MBITS >> (SH + 2)) & 1u) ? e2 : 0.f;                       \
    e3 = ((MBITS >> (SH + 3)) & 1u) ? e3 : 0.f;                       \
    lacc[LI] += (e0 + e1) + (e2 + e3);                                \
    PW0 = cvt_pk_bf16(e0, e1); PW1 = cvt_pk_bf16(e2, e3);             \
  } while (0)

  // TILE: softmax for tile JT (mask word prefetched in am_n), MFMA with BUF.
#define TILE(BUF, JT, JNEXT) do {                                     \
    const u64 am_ = am_n;                                             \
    am_n = brow[JNEXT];                                               \
    const float* dp_ = dT + (JT) * 64 + j0;                           \
    const unsigned amlo_ = (unsigned)(am_ >> j0);                     \
    const unsigned amhi_ = (unsigned)(am_ >> (32 + j0));              \
    union { unsigned w_[4]; s16x8 v_; } P0, P1;                       \
    QUAD(dp_,      amlo_, 0, P0.w_[0], P0.w_[1], 0);                  \
    QUAD(dp_ + 4,  amlo_, 4, P0.w_[2], P0.w_[3], 1);                  \
    QUAD(dp_ + 32, amhi_, 0, P1.w_[0], P1.w_[1], 2);                  \
    QUAD(dp_ + 36, amhi_, 4, P1.w_[2], P1.w_[3], 3);                  \
    _Pragma("unroll")                                                 \
    for (int fb = 0; fb < 4; ++fb) {                                  \
      acc[fb] = __builtin_amdgcn_mfma_f32_16x16x32_bf16(BUF[fb][0], P0.v_, acc[fb], 0, 0, 0); \
      acc[fb] = __builtin_amdgcn_mfma_f32_16x16x32_bf16(BUF[fb][1], P1.v_, acc[fb], 0, 0, 0); \
    }                                                                 \
  } while (0)

  s16x8 bufA[4][2], bufB[4][2];
  LOADA(bufA, jt0);
  u64 am_n = brow[jt0];

  for (int it = 0; it < 16; ++it) {
    const int jA = jt0 + 2 * it;
    const int jB = jA + 1;
    const int jC = (it < 15) ? jB + 1 : jB;   // clamped at the end
    // half A: issue jB's A-loads, process jA from bufA
    LOADA(bufB, jB);
    TILE(bufA, jA, jB);
    // half B: issue jC's A-loads, process jB from bufB
    LOADA(bufA, jC);
    TILE(bufB, jB, jC);
  }
#undef LOADA
#undef QUAD
#undef TILE

  // l for this wave's j-half: sum 4 partials, then over the 4 g-groups
  float l_run = (lacc[0] + lacc[1]) + (lacc[2] + lacc[3]);
  l_run += __shfl_xor(l_run, 16);
  l_run += __shfl_xor(l_run, 32);

  // epilogue: plain-add merge of the two j-halves (same m!), then head-mean
  if (jsw == 1) {
#pragma unroll
    for (int fb = 0; fb < 4; ++fb)
#pragma unroll
      for (int r = 0; r < 4; ++r)
        Abuf[h][i_loc][fb * 16 + g * 4 + r] = acc[fb][r];
    if (lane < 16) Lbuf[h][i_loc] = l_run;
  }
  __syncthreads();
  if (jsw == 0) {
    float invL = 1.f / (l_run + Lbuf[h][i_loc]);
#pragma unroll
    for (int fb = 0; fb < 4; ++fb)
#pragma unroll
      for (int r = 0; r < 4; ++r) {
        int f = fb * 16 + g * 4 + r;
        Abuf[h][i_loc][f] = (acc[fb][r] + Abuf[h][i_loc][f]) * invL;
      }
  }
  __syncthreads();
  {
    int i = t >> 6, f = t & 63;
    float s = 0.f;
#pragma unroll
    for (int hh = 0; hh < 8; ++hh) s += Abuf[hh][i][f];
    out[(size_t)(blk * 16 + i) * 64 + f] = s * 0.125f;
  }
}

extern "C" void kernel_launch(void* const* d_in, const int* in_sizes, int n_in,
                              void* d_out, int out_size, void* d_ws, size_t ws_size,
                              hipStream_t stream)
{
  const float* x = (const float*)d_in[0];
  const void* adj = d_in[1];
  const float* W = (const float*)d_in[2];
  const float* a_src = (const float*)d_in[3];
  const float* a_dst = (const float*)d_in[4];
  float* out = (float*)d_out;

  char* ws = (char*)d_ws;
  float* Hf = (float*)ws;                                   // 8 MB
  u16* Hbt = (u16*)(ws + 8 * 1024 * 1024);                  // 4 MB  [8][64][64][64] bf16 tiled
  float* s_srcT = (float*)(ws + 12 * 1024 * 1024);          // 128 KB [8][4096]
  float* s_dstT = (float*)(ws + 12 * 1024 * 1024 + 128 * 1024);
  int* flag = (int*)(ws + 12 * 1024 * 1024 + 256 * 1024);
  float* Mh = (float*)(ws + 12 * 1024 * 1024 + 384 * 1024); // 32 B
  u64* bits = (u64*)(ws + 12 * 1024 * 1024 + 512 * 1024);   // 2 MB

  gat_detect<<<1, 64, 0, stream>>>(adj, flag);
  gat_pack<<<2048, 256, 0, stream>>>(adj, flag, bits);
  gat_gemm1<<<dim3(64, 8), 256, 0, stream>>>(x, W, Hf, Hbt);
  gat_scores<<<1024, 256, 0, stream>>>(Hf, a_src, a_dst, s_srcT, s_dstT);
  gat_dmax<<<1, 512, 0, stream>>>(s_dstT, Mh);
  gat_flash<<<256, 1024, 0, stream>>>(bits, Hbt, s_srcT, s_dstT, Mh, out);
}